// Round 17
// baseline (118.359 us; speedup 1.0000x reference)
//
#include <hip/hip_runtime.h>
#include <math.h>

#define B_   32
#define T_   1024
#define IN_  512
#define HID_ 512
#define HYP_ 256
#define M_   (B_ * T_)   // 32768
#define R_   128         // rows per fused block -> 256 blocks = 1/CU
#define NSEG 8
#define SEGL 128         // T_/NSEG == R_ -> one block = one segment
#define NCH  (B_ * HID_) // 16384 chains

// LDS map (bytes): H1S 64K | H2S 64K | STG 32K = 160 KiB exactly.
// Phase-dead buffer plan (each slot verified dead at staging time):
//  P1 : A(x fp32) dbuf -> H2S+0 / H2S+32K; W even->STG, odd->H1S+0
//  P2 : A=h1 (H1S, written by P1 epi); W even->STG, odd->H2S+0
//  fc : BOTH halves (8 steps, accf0+accf1); A=h2 (H2S); W even->STG,
//       odd->H1S+0; s=7 pre-stages sig-h0 A0->H1S+32K + W0->STG
//  sig: BK=64, h2 dead; A(x fp32) dbuf -> H2S+0 / H2S+32K; W even->STG,
//       odd->H1S+0. half0 then half1 (tile0 pre-staged across boundary).
#define H1S  0
#define H2S  65536
#define STG  131072
#define LDS_BYTES 163840

typedef _Float16 half8_t __attribute__((ext_vector_type(8)));
typedef float    f32x4   __attribute__((ext_vector_type(4)));

typedef __attribute__((address_space(1))) const void* gptr_as1;
typedef __attribute__((address_space(3))) void*       lptr_as3;

__device__ __forceinline__ void gload_lds16(const void* g, void* l) {
    __builtin_amdgcn_global_load_lds((gptr_as1)g, (lptr_as3)l, 16, 0, 0);
}

// counted-vmcnt (T4): literal = loads intentionally left in flight.
#define VMCNT8() asm volatile("s_waitcnt vmcnt(8)" ::: "memory")
#define VMCNT4() asm volatile("s_waitcnt vmcnt(4)" ::: "memory")
#define VMCNT0() asm volatile("s_waitcnt vmcnt(0)" ::: "memory")
#define SBAR()   __builtin_amdgcn_s_barrier()
#define SCHED0() __builtin_amdgcn_sched_barrier(0)

// ---------------------------------------------------------------------------
// fp32 -> fp16 weights only (~1.3 MB out). 2048 elems/block.
// ---------------------------------------------------------------------------
__global__ __launch_bounds__(256) void cvt_w(
    const float* __restrict__ Ws, _Float16* __restrict__ wsh,
    const float* __restrict__ Wm, _Float16* __restrict__ wmh,
    const float* __restrict__ We, _Float16* __restrict__ weh,
    const float* __restrict__ W2, _Float16* __restrict__ w2h)
{
    const int blk = blockIdx.x;
    const float* src; _Float16* dst; int base;
    if      (blk < 64)  { src = Ws; dst = wsh; base = blk; }
    else if (blk < 96)  { src = Wm; dst = wmh; base = blk - 64; }
    else if (blk < 160) { src = We; dst = weh; base = blk - 96; }
    else                { src = W2; dst = w2h; base = blk - 160; }
    const int i = base * 2048 + threadIdx.x * 8;
    f32x4 v0 = *(const f32x4*)(src + i);
    f32x4 v1 = *(const f32x4*)(src + i + 4);
    half8_t h;
    h[0] = (_Float16)v0[0]; h[1] = (_Float16)v0[1];
    h[2] = (_Float16)v0[2]; h[3] = (_Float16)v0[3];
    h[4] = (_Float16)v1[0]; h[5] = (_Float16)v1[1];
    h[6] = (_Float16)v1[2]; h[7] = (_Float16)v1[3];
    *(half8_t*)(dst + i) = h;
}

// ---------------------------------------------------------------------------
// Fragment-order + XOR-swizzled W staging (proven r8 layout).
// ---------------------------------------------------------------------------
__device__ __forceinline__ void stage512(const _Float16* src, int K,
                                         char* ldsbase, int tid)
{
#pragma unroll
    for (int q = 0; q < 2; ++q) {
        const int s = q * 512 + tid;
        const int g = s >> 6, c2 = (s >> 4) & 3, r = (s & 15) ^ c2;
        const char* gp = (const char*)src + (size_t)(g * 16 + r) * (K * 2) + c2 * 16;
        char* lp = ldsbase + (q * 512 + (tid & ~63)) * 16;
        gload_lds16(gp, lp);
    }
}

__device__ __forceinline__ void stageW64(const _Float16* src, int K,
                                         char* ldsbase, int tid)
{
    stage512(src,      K, ldsbase,         tid);
    stage512(src + 32, K, ldsbase + 16384, tid);
}

// ---------------------------------------------------------------------------
// fp32 A staging via gload_lds, plane-split (proven r14). BK=32 sub-tile =
// two 8 KiB planes; same slot map + XOR swizzle as fp16 tiles.
// ---------------------------------------------------------------------------
__device__ __forceinline__ void stageA32(const float* src, int K,
                                         char* ldsbase, int tid)
{
#pragma unroll
    for (int p = 0; p < 2; ++p) {
        const int g = tid >> 6, c2 = (tid >> 4) & 3, r = (tid & 15) ^ c2;
        const char* gp = (const char*)(src + (size_t)(g * 16 + r) * K + c2 * 8 + p * 4);
        char* lp = ldsbase + p * 8192 + (tid & ~63) * 16;
        gload_lds16(gp, lp);
    }
}

__device__ __forceinline__ void stageA32_64(const float* src, int K,
                                            char* ldsbase, int tid)
{
    stageA32(src,      K, ldsbase,         tid);
    stageA32(src + 32, K, ldsbase + 16384, tid);
}

__device__ __forceinline__ half8_t cvt8(f32x4 a, f32x4 b)
{
    half8_t h;
    h[0] = (_Float16)a[0]; h[1] = (_Float16)a[1];
    h[2] = (_Float16)a[2]; h[3] = (_Float16)a[3];
    h[4] = (_Float16)b[0]; h[5] = (_Float16)b[1];
    h[6] = (_Float16)b[2]; h[7] = (_Float16)b[3];
    return h;
}

// 16 MFMAs, fp16 A sub-tile
__device__ __forceinline__ void do_step16(const char* ab, const char* bb,
                                          int wm, int wn, int lsw,
                                          f32x4 acc[4][4])
{
    half8_t af[4], wf[4];
#pragma unroll
    for (int i = 0; i < 4; ++i)
        af[i] = *(const half8_t*)(ab + (wm * 4 + i) * 1024 + lsw);
#pragma unroll
    for (int j = 0; j < 4; ++j)
        wf[j] = *(const half8_t*)(bb + (wn * 4 + j) * 1024 + lsw);
#pragma unroll
    for (int i = 0; i < 4; ++i)
#pragma unroll
        for (int j = 0; j < 4; ++j)
            acc[i][j] = __builtin_amdgcn_mfma_f32_16x16x32_f16(af[i], wf[j], acc[i][j], 0, 0, 0);
}

__device__ __forceinline__ void do_step32(const char* ab, const char* bb,
                                          int wm, int wn, int lsw,
                                          f32x4 acc[4][4])
{
    do_step16(ab,         bb,         wm, wn, lsw, acc);
    do_step16(ab + 8192,  bb + 16384, wm, wn, lsw, acc);
}

// 16 MFMAs, fp32 A sub-tile (x paths)
__device__ __forceinline__ void do_step16_fa(const char* ab, const char* bb,
                                             int wm, int wn, int lsw,
                                             f32x4 acc[4][4])
{
    half8_t af[4], wf[4];
#pragma unroll
    for (int i = 0; i < 4; ++i) {
        f32x4 p0 = *(const f32x4*)(ab + (wm * 4 + i) * 1024 + lsw);
        f32x4 p1 = *(const f32x4*)(ab + 8192 + (wm * 4 + i) * 1024 + lsw);
        af[i] = cvt8(p0, p1);
    }
#pragma unroll
    for (int j = 0; j < 4; ++j)
        wf[j] = *(const half8_t*)(bb + (wn * 4 + j) * 1024 + lsw);
#pragma unroll
    for (int i = 0; i < 4; ++i)
#pragma unroll
        for (int j = 0; j < 4; ++j)
            acc[i][j] = __builtin_amdgcn_mfma_f32_16x16x32_f16(af[i], wf[j], acc[i][j], 0, 0, 0);
}

__device__ __forceinline__ void do_step32_fa(const char* ab, const char* bb,
                                             int wm, int wn, int lsw,
                                             f32x4 acc[4][4])
{
    do_step16_fa(ab,          bb,         wm, wn, lsw, acc);
    do_step16_fa(ab + 16384,  bb + 16384, wm, wn, lsw, acc);
}

// bias+relu epilogue: scatter fp16 into XOR-swizzled fragment-order LDS
__device__ __forceinline__ void epi_relu_lds(char* dst, const f32x4 acc[4][4],
                                             const float* __restrict__ bias,
                                             int wm, int wn, int lq, int lr)
{
#pragma unroll
    for (int j = 0; j < 4; ++j) {
        const int col = wn * 64 + j * 16 + lr;
        const float bv = bias[col];
        const int cc2 = (col & 31) >> 3;
        const int cpart = (col >> 5) * 8192 + cc2 * 256 + (col & 7) * 2;
#pragma unroll
        for (int i = 0; i < 4; ++i) {
#pragma unroll
            for (int rg = 0; rg < 4; ++rg) {
                const int row = wm * 64 + i * 16 + lq * 4 + rg;
                const float v = fmaxf(acc[i][j][rg] + bv, 0.f);
                *(_Float16*)(dst + cpart + (row >> 4) * 1024 +
                             (((row & 15) ^ cc2)) * 16) = (_Float16)v;
            }
        }
    }
}

// output epilogue: bh(fp16) = (fc + be) * sigmoid(sig + b2) for one 256-col half
__device__ __forceinline__ void epi_bh(_Float16* __restrict__ bh,
                                       const f32x4 accf[4][4], const f32x4 accs[4][4],
                                       const float* __restrict__ be,
                                       const float* __restrict__ b2,
                                       int m0, int c0, int wm, int wn, int lq, int lr)
{
#pragma unroll
    for (int j = 0; j < 4; ++j) {
        const int gcol = c0 + wn * 64 + j * 16 + lr;
        const float bev = be[gcol];
        const float b2v = b2[gcol];
#pragma unroll
        for (int i = 0; i < 4; ++i) {
#pragma unroll
            for (int rg = 0; rg < 4; ++rg) {
                const int row = m0 + wm * 64 + i * 16 + lq * 4 + rg;
                const float fc = accf[i][j][rg] + bev;
                float sg = accs[i][j][rg] + b2v;
                sg = 1.f / (1.f + __expf(-sg));
                bh[(size_t)row * HID_ + gcol] = (_Float16)(fc * sg);
            }
        }
    }
}

// ---------------------------------------------------------------------------
// Fused MLP, 36-step schedule (r12 step count, fp32-x staging, fc-both-first):
//   P1 : h1 = relu(x@Ws^T+bs)   8 BK=64 steps, VMCNT(8)
//   P2 : h2 = relu(h1@Wm^T+bm)  4 BK=64 steps, VMCNT(4)
//   fc : BOTH halves, 8 BK=64 steps -> accf0/accf1 (h2 consumed, then dead)
//   sig: half0 8 + half1 8 BK=64 steps (A = x fp32, dbuf in freed H2S)
// + in-kernel segment (S,D) reduction tail (replaces seg_reduce kernel).
// ---------------------------------------------------------------------------
__global__ __launch_bounds__(512, 2) void fused_mlp(
    const float* __restrict__ x,
    const _Float16* __restrict__ wsh, const float* __restrict__ bs,
    const _Float16* __restrict__ wmh, const float* __restrict__ bm,
    const _Float16* __restrict__ weh, const float* __restrict__ be,
    const _Float16* __restrict__ w2h, const float* __restrict__ b2,
    _Float16* __restrict__ bh,
    float* __restrict__ Sarr, float* __restrict__ Darr)
{
    __shared__ __align__(16) char lds[LDS_BYTES];

    const int tid  = threadIdx.x;
    const int m0   = blockIdx.x * R_;
    const int lane = tid & 63;
    const int wave = tid >> 6;
    const int wm = wave >> 2;
    const int wn = wave & 3;
    const int lq = lane >> 4, lr = lane & 15;
    const int lsw = (lane ^ ((lane >> 4) & 3)) * 16;

    const float* xrow = x + (size_t)m0 * IN_;
    const f32x4 zero = {0.f, 0.f, 0.f, 0.f};

    // ---- P1: h1 = relu(x @ Ws^T + bs), K=512, 8 BK=64 steps ----
    {
        f32x4 acc[4][4];
#pragma unroll
        for (int i = 0; i < 4; ++i)
#pragma unroll
            for (int j = 0; j < 4; ++j) acc[i][j] = zero;

        stageA32_64(xrow, IN_, lds + H2S, tid);       // A0 -> H2S slot0
        stageW64(wsh, IN_, lds + STG, tid);           // W0 even -> STG
        __syncthreads();                              // drain prologue

        for (int s = 0; s < 7; ++s) {
            const int e = s + 1;
            stageA32_64(xrow + e * 64, IN_, lds + H2S + (e & 1) * 32768, tid);
            stageW64(wsh + e * 64, IN_, (e & 1) ? lds + H1S : lds + STG, tid);
            SCHED0(); VMCNT8(); SCHED0(); SBAR(); SCHED0();
            const char* ab = lds + H2S + (s & 1) * 32768;
            const char* bb = (s & 1) ? lds + H1S : lds + STG;
            __builtin_amdgcn_s_setprio(1);
            do_step32_fa(ab, bb, wm, wn, lsw, acc);
            __builtin_amdgcn_s_setprio(0);
            SCHED0(); SBAR(); SCHED0();
        }
        // s=7 (odd): pre-stage P2's W0 -> STG
        stageW64(wmh, HYP_, lds + STG, tid);
        SCHED0(); VMCNT4(); SCHED0(); SBAR(); SCHED0();
        __builtin_amdgcn_s_setprio(1);
        do_step32_fa(lds + H2S + 32768, lds + H1S, wm, wn, lsw, acc);
        __builtin_amdgcn_s_setprio(0);
        __syncthreads();
        epi_relu_lds(lds + H1S, acc, bs, wm, wn, lq, lr);
        __syncthreads();
    }

    // ---- P2: h2 = relu(h1 @ Wm^T + bm), K=256, 4 steps ----
    {
        f32x4 acc[4][4];
#pragma unroll
        for (int i = 0; i < 4; ++i)
#pragma unroll
            for (int j = 0; j < 4; ++j) acc[i][j] = zero;

        for (int s = 0; s < 3; ++s) {
            const int e = s + 1;
            stageW64(wmh + e * 64, HYP_, (e & 1) ? lds + H2S : lds + STG, tid);
            SCHED0(); VMCNT4(); SCHED0(); SBAR(); SCHED0();
            const char* ab = lds + H1S + s * 16384;
            const char* bb = (s & 1) ? lds + H2S : lds + STG;
            __builtin_amdgcn_s_setprio(1);
            do_step32(ab, bb, wm, wn, lsw, acc);
            __builtin_amdgcn_s_setprio(0);
            SCHED0(); SBAR(); SCHED0();
        }
        // s=3 (odd): pre-stage fc W0 (weh half0 tile0) -> STG
        stageW64(weh, HYP_, lds + STG, tid);
        SCHED0(); VMCNT4(); SCHED0(); SBAR(); SCHED0();
        __builtin_amdgcn_s_setprio(1);
        do_step32(lds + H1S + 49152, lds + H2S, wm, wn, lsw, acc);
        __builtin_amdgcn_s_setprio(0);
        __syncthreads();
        epi_relu_lds(lds + H2S, acc, bm, wm, wn, lq, lr);
        __syncthreads();
    }

    // ---- fc + sig accumulators (live through the rest of the kernel) ----
    f32x4 accf0[4][4], accf1[4][4], accs[4][4];
#pragma unroll
    for (int i = 0; i < 4; ++i)
#pragma unroll
        for (int j = 0; j < 4; ++j) { accf0[i][j] = zero; accf1[i][j] = zero; }

    // ---- fc: BOTH halves, 8 BK=64 steps, A=h2 @H2S ----
    {
        // half0 -> accf0 (global steps 0..3); W0 pre-staged in STG
        for (int s = 0; s < 4; ++s) {
            const int e = s + 1;                     // 1..4
            const _Float16* wsrc = (e < 4) ? (weh + e * 64)
                                           : (weh + (size_t)256 * HYP_);
            stageW64(wsrc, HYP_, (e & 1) ? lds + H1S : lds + STG, tid);
            SCHED0(); VMCNT4(); SCHED0(); SBAR(); SCHED0();
            const char* ab = lds + H2S + s * 16384;
            const char* bb = (s & 1) ? lds + H1S : lds + STG;
            __builtin_amdgcn_s_setprio(1);
            do_step32(ab, bb, wm, wn, lsw, accf0);
            __builtin_amdgcn_s_setprio(0);
            SCHED0(); SBAR(); SCHED0();
        }
        // half1 -> accf1 (global steps 4..6); A chunks 0..2
        for (int s = 0; s < 3; ++s) {
            const int gs = 4 + s;
            const int e = gs + 1;                    // 5..7
            stageW64(weh + (size_t)256 * HYP_ + (e - 4) * 64, HYP_,
                     (e & 1) ? lds + H1S : lds + STG, tid);
            SCHED0(); VMCNT4(); SCHED0(); SBAR(); SCHED0();
            const char* ab = lds + H2S + s * 16384;
            const char* bb = (gs & 1) ? lds + H1S : lds + STG;
            __builtin_amdgcn_s_setprio(1);
            do_step32(ab, bb, wm, wn, lsw, accf1);
            __builtin_amdgcn_s_setprio(0);
            SCHED0(); SBAR(); SCHED0();
        }
        // gs=7 (odd, W7 @H1S+0): pre-stage sig-h0 A0 -> H1S+32K, W2h0t0 -> STG
        stageA32_64(xrow, IN_, lds + H1S + 32768, tid);
        stageW64(w2h, IN_, lds + STG, tid);
        SCHED0(); VMCNT8(); SCHED0(); SBAR(); SCHED0();
        __builtin_amdgcn_s_setprio(1);
        do_step32(lds + H2S + 49152, lds + H1S, wm, wn, lsw, accf1);
        __builtin_amdgcn_s_setprio(0);
        SCHED0(); SBAR(); SCHED0();
    }

    // ---- sig half0: 8 BK=64 steps, A = x fp32 (dbuf in freed H2S) ----
#pragma unroll
    for (int i = 0; i < 4; ++i)
#pragma unroll
        for (int j = 0; j < 4; ++j) accs[i][j] = zero;
    {
        for (int s = 0; s < 8; ++s) {
            if (s < 7) {
                const int e = s + 1;
                stageA32_64(xrow + e * 64, IN_,
                            (e & 1) ? lds + H2S : lds + H2S + 32768, tid);
                stageW64(w2h + e * 64, IN_, (e & 1) ? lds + H1S : lds + STG, tid);
            } else {
                // s=7: pre-stage half1 tile0 (A6@H2S+32K and W6@STG dead)
                stageA32_64(xrow, IN_, lds + H2S + 32768, tid);
                stageW64(w2h + (size_t)256 * IN_, IN_, lds + STG, tid);
            }
            SCHED0(); VMCNT8(); SCHED0(); SBAR(); SCHED0();
            const char* ab = (s == 0) ? lds + H1S + 32768
                           : ((s & 1) ? lds + H2S : lds + H2S + 32768);
            const char* bb = (s & 1) ? lds + H1S : lds + STG;
            __builtin_amdgcn_s_setprio(1);
            do_step32_fa(ab, bb, wm, wn, lsw, accs);
            __builtin_amdgcn_s_setprio(0);
            SCHED0(); SBAR(); SCHED0();
        }
        // epilogue half0 (stores drain via the next counted vmcnt / syncs)
        epi_bh(bh, accf0, accs, be, b2, m0, 0, wm, wn, lq, lr);
    }

    // ---- sig half1: 8 BK=64 steps (tile0 pre-staged at half0 s=7) ----
#pragma unroll
    for (int i = 0; i < 4; ++i)
#pragma unroll
        for (int j = 0; j < 4; ++j) accs[i][j] = zero;
    {
        for (int s = 0; s < 8; ++s) {
            if (s < 7) {
                const int e = s + 1;
                stageA32_64(xrow + e * 64, IN_,
                            (e & 1) ? lds + H2S : lds + H2S + 32768, tid);
                stageW64(w2h + (size_t)256 * IN_ + e * 64, IN_,
                         (e & 1) ? lds + H1S : lds + STG, tid);
                SCHED0(); VMCNT8(); SCHED0(); SBAR(); SCHED0();
            } else {
                VMCNT0(); SCHED0(); SBAR(); SCHED0();
            }
            const char* ab = (s == 0) ? lds + H2S + 32768
                           : ((s & 1) ? lds + H2S : lds + H2S + 32768);
            const char* bb = (s & 1) ? lds + H1S : lds + STG;
            __builtin_amdgcn_s_setprio(1);
            do_step32_fa(ab, bb, wm, wn, lsw, accs);
            __builtin_amdgcn_s_setprio(0);
            SCHED0(); SBAR(); SCHED0();
        }
        epi_bh(bh, accf1, accs, be, b2, m0, 256, wm, wn, lq, lr);
        __syncthreads();   // drains bh stores before the tail reads them
    }

    // ---- tail: per-block segment (S,D) reduction (replaces seg_reduce) ----
    {
        const int bb_ = m0 >> 10;          // batch
        const int t0  = m0 & 1023;         // segment start time
        const int seg = t0 >> 7;
        const int r   = tid;               // chain within batch
        const _Float16* bp = bh + (size_t)m0 * HID_;
        float S = 0.f, D = -__builtin_inff();
#pragma unroll 8
        for (int u = 0; u < SEGL; ++u) {
            const float v = (float)bp[u * 512 + ((r + t0 + u) & 511)];
            S += v;
            D = fmaxf(D + v, 0.f);
        }
        Sarr[seg * NCH + bb_ * 512 + r] = S;
        Darr[seg * NCH + bb_ * 512 + r] = D;
    }
}

// ---------------------------------------------------------------------------
// Segmented max-plus scan (proven r11).
// ---------------------------------------------------------------------------
__global__ __launch_bounds__(64) void carry_scan(const float* __restrict__ hidden,
                                                 const float* __restrict__ Sarr,
                                                 const float* __restrict__ Darr,
                                                 float* __restrict__ carry,
                                                 float* __restrict__ hlast)
{
    const int chain = blockIdx.x * 64 + threadIdx.x;
    const int b = chain >> 9, r = chain & 511;
    float c = hidden[b * 512 + ((r + 511) & 511)];
#pragma unroll
    for (int j = 0; j < NSEG; ++j) {
        carry[j * NCH + chain] = c;
        c = fmaxf(c + Sarr[j * NCH + chain], Darr[j * NCH + chain]);
    }
    hlast[b * 512 + ((r + 1023) & 511)] = c;
}

__global__ __launch_bounds__(256) void seg_apply(const _Float16* __restrict__ bh,
                                                 const float* __restrict__ carry,
                                                 float* __restrict__ out)
{
    const int G = blockIdx.x * 256 + threadIdx.x;
    const int r = G & 511;
    const int seg = (G >> 9) & 7;
    const int b = G >> 12;
    const int chain = b * 512 + r;
    const _Float16* bb = bh + (size_t)b * (T_ * HID_);
    float* ob = out + (size_t)b * (T_ * HID_);
    const int t0 = seg * SEGL;

    float c = carry[seg * NCH + chain];
#pragma unroll 8
    for (int u = 0; u < SEGL; ++u) {
        const int t = t0 + u;
        const int idx = t * 512 + ((r + t) & 511);
        c = fmaxf(c + (float)bb[idx], 0.f);
        ob[idx] = c;
    }
}

extern "C" void kernel_launch(void* const* d_in, const int* in_sizes, int n_in,
                              void* d_out, int out_size, void* d_ws, size_t ws_size,
                              hipStream_t stream)
{
    const float* x      = (const float*)d_in[0];  // [B,T,IN]
    const float* hidden = (const float*)d_in[1];  // [B,HID]
    const float* Ws     = (const float*)d_in[2];  // [HYP,IN]
    const float* bs     = (const float*)d_in[3];
    const float* Wm     = (const float*)d_in[4];  // [HYP,HYP]
    const float* bm     = (const float*)d_in[5];
    const float* We     = (const float*)d_in[6];  // [HID,HYP]
    const float* be     = (const float*)d_in[7];
    const float* W2     = (const float*)d_in[8];  // [HID,IN]
    const float* b2     = (const float*)d_in[9];

    float* outputs = (float*)d_out;                 // [B,T,HID]
    float* hlast   = outputs + (size_t)M_ * HID_;   // [B,HID]

    // workspace: bh 32MB | weights 1.3MB | S,D,carry 1.5MB
    _Float16* bh   = (_Float16*)d_ws;
    _Float16* wsh  = bh + (size_t)M_ * HID_;        // [HYP,IN]
    _Float16* wmh  = wsh + HYP_ * IN_;              // [HYP,HYP]
    _Float16* weh  = wmh + HYP_ * HYP_;             // [HID,HYP]
    _Float16* w2h  = weh + HID_ * HYP_;             // [HID,IN]
    float*    Sarr = (float*)(w2h + HID_ * IN_);    // [NSEG, NCH]
    float*    Darr = Sarr + NSEG * NCH;             // [NSEG, NCH]
    float*    carr = Darr + NSEG * NCH;             // [NSEG, NCH]

    cvt_w<<<dim3(288), 256, 0, stream>>>(Ws, wsh, Wm, wmh, We, weh, W2, w2h);
    fused_mlp<<<dim3(M_ / R_), 512, 0, stream>>>(
        x, wsh, bs, wmh, bm, weh, be, w2h, b2, bh, Sarr, Darr);
    carry_scan<<<dim3(NCH / 64), 64, 0, stream>>>(hidden, Sarr, Darr, carr, hlast);
    seg_apply<<<dim3((NCH * NSEG) / 256), 256, 0, stream>>>(bh, carr, outputs);
}

// Round 18
// 111.244 us; speedup vs baseline: 1.0640x; 1.0640x over previous
//
#include <hip/hip_runtime.h>
#include <math.h>

#define B_   32
#define T_   1024
#define IN_  512
#define HID_ 512
#define HYP_ 256
#define M_   (B_ * T_)   // 32768
#define R_   128         // rows per fused block -> 256 blocks = 1/CU
#define NSEG 8
#define SEGL 128         // T_/NSEG == R_ -> one block = one segment
#define NCH  (B_ * HID_) // 16384 chains

// LDS map (bytes): H1S 64K | H2S 64K | STG 32K = 160 KiB exactly.
// Phase-dead buffer plan (each slot verified dead at staging time):
//  P1 : A(x fp32) dbuf -> H2S+0 / H2S+32K; W even->STG, odd->H1S+0
//  P2 : A=h1 (H1S, written by P1 epi); W even->STG, odd->H2S+0
//  fc : A=h2 (H2S, written by P2 epi); W even->STG, odd->H1S+0
//  sig: BK=32; A(x fp32) dbuf -> H1S+32K / H1S+48K; W even->STG+0,
//       odd->H1S+0.  H2S (h2) untouched -> survives for half 1.
#define H1S  0
#define H2S  65536
#define STG  131072
#define LDS_BYTES 163840

typedef _Float16 half8_t __attribute__((ext_vector_type(8)));
typedef float    f32x4   __attribute__((ext_vector_type(4)));

typedef __attribute__((address_space(1))) const void* gptr_as1;
typedef __attribute__((address_space(3))) void*       lptr_as3;

__device__ __forceinline__ void gload_lds16(const void* g, void* l) {
    __builtin_amdgcn_global_load_lds((gptr_as1)g, (lptr_as3)l, 16, 0, 0);
}

// counted-vmcnt (T4): literal = loads intentionally left in flight.
#define VMCNT8() asm volatile("s_waitcnt vmcnt(8)" ::: "memory")
#define VMCNT4() asm volatile("s_waitcnt vmcnt(4)" ::: "memory")
#define VMCNT0() asm volatile("s_waitcnt vmcnt(0)" ::: "memory")
#define SBAR()   __builtin_amdgcn_s_barrier()
#define SCHED0() __builtin_amdgcn_sched_barrier(0)

// ---------------------------------------------------------------------------
// fp32 -> fp16 weights only (~1.3 MB out). 2048 elems/block.
// Ws 131072 | Wm 65536 | We 131072 | W2 262144 -> 64|32|64|128 blocks.
// ---------------------------------------------------------------------------
__global__ __launch_bounds__(256) void cvt_w(
    const float* __restrict__ Ws, _Float16* __restrict__ wsh,
    const float* __restrict__ Wm, _Float16* __restrict__ wmh,
    const float* __restrict__ We, _Float16* __restrict__ weh,
    const float* __restrict__ W2, _Float16* __restrict__ w2h)
{
    const int blk = blockIdx.x;
    const float* src; _Float16* dst; int base;
    if      (blk < 64)  { src = Ws; dst = wsh; base = blk; }
    else if (blk < 96)  { src = Wm; dst = wmh; base = blk - 64; }
    else if (blk < 160) { src = We; dst = weh; base = blk - 96; }
    else                { src = W2; dst = w2h; base = blk - 160; }
    const int i = base * 2048 + threadIdx.x * 8;
    f32x4 v0 = *(const f32x4*)(src + i);
    f32x4 v1 = *(const f32x4*)(src + i + 4);
    half8_t h;
    h[0] = (_Float16)v0[0]; h[1] = (_Float16)v0[1];
    h[2] = (_Float16)v0[2]; h[3] = (_Float16)v0[3];
    h[4] = (_Float16)v1[0]; h[5] = (_Float16)v1[1];
    h[6] = (_Float16)v1[2]; h[7] = (_Float16)v1[3];
    *(half8_t*)(dst + i) = h;
}

// ---------------------------------------------------------------------------
// Fragment-order + XOR-swizzled W staging (proven r8 layout).
// stage512: 256-row x 32-half W sub-tile (16 KiB), 2 gload_lds/thread.
// stageW64: 64-half W tile (32 KiB) = two sub-tiles -> 4/thread.
// ---------------------------------------------------------------------------
__device__ __forceinline__ void stage512(const _Float16* src, int K,
                                         char* ldsbase, int tid)
{
#pragma unroll
    for (int q = 0; q < 2; ++q) {
        const int s = q * 512 + tid;
        const int g = s >> 6, c2 = (s >> 4) & 3, r = (s & 15) ^ c2;
        const char* gp = (const char*)src + (size_t)(g * 16 + r) * (K * 2) + c2 * 16;
        char* lp = ldsbase + (q * 512 + (tid & ~63)) * 16;
        gload_lds16(gp, lp);
    }
}

__device__ __forceinline__ void stageW64(const _Float16* src, int K,
                                         char* ldsbase, int tid)
{
    stage512(src,      K, ldsbase,         tid);
    stage512(src + 32, K, ldsbase + 16384, tid);
}

// ---------------------------------------------------------------------------
// fp32 A staging via gload_lds, plane-split: one BK=32 sub-tile (128 rows x
// 32 floats) = 16 KiB = two 8 KiB planes; plane p holds floats k%8 in
// [4p,4p+4). Each plane uses the SAME slot map + XOR swizzle as the fp16
// tile (16B slot = 4 floats), so the proven conflict-free read offset lsw
// applies unchanged. 2 gload_lds/thread per sub-tile. ASYNC.
// ---------------------------------------------------------------------------
__device__ __forceinline__ void stageA32(const float* src, int K,
                                         char* ldsbase, int tid)
{
#pragma unroll
    for (int p = 0; p < 2; ++p) {
        const int g = tid >> 6, c2 = (tid >> 4) & 3, r = (tid & 15) ^ c2;
        const char* gp = (const char*)(src + (size_t)(g * 16 + r) * K + c2 * 8 + p * 4);
        char* lp = ldsbase + p * 8192 + (tid & ~63) * 16;
        gload_lds16(gp, lp);
    }
}

// BK=64 fp32 A tile (32 KiB): two sub-tiles at +0 / +16K -> 4 loads/thread
__device__ __forceinline__ void stageA32_64(const float* src, int K,
                                            char* ldsbase, int tid)
{
    stageA32(src,      K, ldsbase,         tid);
    stageA32(src + 32, K, ldsbase + 16384, tid);
}

__device__ __forceinline__ half8_t cvt8(f32x4 a, f32x4 b)
{
    half8_t h;
    h[0] = (_Float16)a[0]; h[1] = (_Float16)a[1];
    h[2] = (_Float16)a[2]; h[3] = (_Float16)a[3];
    h[4] = (_Float16)b[0]; h[5] = (_Float16)b[1];
    h[6] = (_Float16)b[2]; h[7] = (_Float16)b[3];
    return h;
}

// 16 MFMAs, fp16 A sub-tile (h1/h2 paths)
__device__ __forceinline__ void do_step16(const char* ab, const char* bb,
                                          int wm, int wn, int lsw,
                                          f32x4 acc[4][4])
{
    half8_t af[4], wf[4];
#pragma unroll
    for (int i = 0; i < 4; ++i)
        af[i] = *(const half8_t*)(ab + (wm * 4 + i) * 1024 + lsw);
#pragma unroll
    for (int j = 0; j < 4; ++j)
        wf[j] = *(const half8_t*)(bb + (wn * 4 + j) * 1024 + lsw);
#pragma unroll
    for (int i = 0; i < 4; ++i)
#pragma unroll
        for (int j = 0; j < 4; ++j)
            acc[i][j] = __builtin_amdgcn_mfma_f32_16x16x32_f16(af[i], wf[j], acc[i][j], 0, 0, 0);
}

__device__ __forceinline__ void do_step32(const char* ab, const char* bb,
                                          int wm, int wn, int lsw,
                                          f32x4 acc[4][4])
{
    do_step16(ab,         bb,         wm, wn, lsw, acc);
    do_step16(ab + 8192,  bb + 16384, wm, wn, lsw, acc);
}

// 16 MFMAs, fp32 A sub-tile (x paths): 2 plane reads + cvt per A-frag
__device__ __forceinline__ void do_step16_fa(const char* ab, const char* bb,
                                             int wm, int wn, int lsw,
                                             f32x4 acc[4][4])
{
    half8_t af[4], wf[4];
#pragma unroll
    for (int i = 0; i < 4; ++i) {
        f32x4 p0 = *(const f32x4*)(ab + (wm * 4 + i) * 1024 + lsw);
        f32x4 p1 = *(const f32x4*)(ab + 8192 + (wm * 4 + i) * 1024 + lsw);
        af[i] = cvt8(p0, p1);
    }
#pragma unroll
    for (int j = 0; j < 4; ++j)
        wf[j] = *(const half8_t*)(bb + (wn * 4 + j) * 1024 + lsw);
#pragma unroll
    for (int i = 0; i < 4; ++i)
#pragma unroll
        for (int j = 0; j < 4; ++j)
            acc[i][j] = __builtin_amdgcn_mfma_f32_16x16x32_f16(af[i], wf[j], acc[i][j], 0, 0, 0);
}

__device__ __forceinline__ void do_step32_fa(const char* ab, const char* bb,
                                             int wm, int wn, int lsw,
                                             f32x4 acc[4][4])
{
    do_step16_fa(ab,          bb,         wm, wn, lsw, acc);
    do_step16_fa(ab + 16384,  bb + 16384, wm, wn, lsw, acc);
}

// bias+relu epilogue: scatter fp16 into XOR-swizzled fragment-order LDS
__device__ __forceinline__ void epi_relu_lds(char* dst, const f32x4 acc[4][4],
                                             const float* __restrict__ bias,
                                             int wm, int wn, int lq, int lr)
{
#pragma unroll
    for (int j = 0; j < 4; ++j) {
        const int col = wn * 64 + j * 16 + lr;
        const float bv = bias[col];
        const int cc2 = (col & 31) >> 3;
        const int cpart = (col >> 5) * 8192 + cc2 * 256 + (col & 7) * 2;
#pragma unroll
        for (int i = 0; i < 4; ++i) {
#pragma unroll
            for (int rg = 0; rg < 4; ++rg) {
                const int row = wm * 64 + i * 16 + lq * 4 + rg;
                const float v = fmaxf(acc[i][j][rg] + bv, 0.f);
                *(_Float16*)(dst + cpart + (row >> 4) * 1024 +
                             (((row & 15) ^ cc2)) * 16) = (_Float16)v;
            }
        }
    }
}

// ---------------------------------------------------------------------------
// Fused MLP (r14 proven structure) + in-kernel segment (S,D) reduction tail.
//   P1 : h1 = relu(x@Ws^T+bs)   K=512, 8 BK=64 steps (A fp32 + W), VMCNT(8)
//   P2 : h2 = relu(h1@Wm^T+bm)  K=256, 4 BK=64 steps, VMCNT(4)
//   fc : (per half) 4 BK=64 steps, A=h2, VMCNT(4)
//   sig: (per half) 16 BK=32 steps, A=x fp32, VMCNT(4)
// Tail: block covers rows t0..t0+127 of batch b = exactly segment t0/128 for
// all 512 chains -> reduce (S,D) from the freshly-written (L2-hot) bh tile.
// ---------------------------------------------------------------------------
__global__ __launch_bounds__(512, 2) void fused_mlp(
    const float* __restrict__ x,
    const _Float16* __restrict__ wsh, const float* __restrict__ bs,
    const _Float16* __restrict__ wmh, const float* __restrict__ bm,
    const _Float16* __restrict__ weh, const float* __restrict__ be,
    const _Float16* __restrict__ w2h, const float* __restrict__ b2,
    _Float16* __restrict__ bh,
    float* __restrict__ Sarr, float* __restrict__ Darr)
{
    __shared__ __align__(16) char lds[LDS_BYTES];

    const int tid  = threadIdx.x;
    const int m0   = blockIdx.x * R_;
    const int lane = tid & 63;
    const int wave = tid >> 6;
    const int wm = wave >> 2;
    const int wn = wave & 3;
    const int lq = lane >> 4, lr = lane & 15;
    const int lsw = (lane ^ ((lane >> 4) & 3)) * 16;

    const float* xrow = x + (size_t)m0 * IN_;
    const f32x4 zero = {0.f, 0.f, 0.f, 0.f};

    // ---- P1: h1 = relu(x @ Ws^T + bs), K=512, 8 steps of 64 ----
    {
        f32x4 acc[4][4];
#pragma unroll
        for (int i = 0; i < 4; ++i)
#pragma unroll
            for (int j = 0; j < 4; ++j) acc[i][j] = zero;

        stageA32_64(xrow, IN_, lds + H2S, tid);       // A0 -> H2S slot0
        stageW64(wsh, IN_, lds + STG, tid);           // W0 even -> STG
        __syncthreads();                              // drain prologue

        for (int s = 0; s < 7; ++s) {
            const int e = s + 1;
            stageA32_64(xrow + e * 64, IN_, lds + H2S + (e & 1) * 32768, tid);
            stageW64(wsh + e * 64, IN_, (e & 1) ? lds + H1S : lds + STG, tid);
            SCHED0(); VMCNT8(); SCHED0(); SBAR(); SCHED0();
            const char* ab = lds + H2S + (s & 1) * 32768;
            const char* bb = (s & 1) ? lds + H1S : lds + STG;
            __builtin_amdgcn_s_setprio(1);
            do_step32_fa(ab, bb, wm, wn, lsw, acc);
            __builtin_amdgcn_s_setprio(0);
            SCHED0(); SBAR(); SCHED0();
        }
        // s=7 (odd): pre-stage P2's W0 -> STG (P1 W6 in STG consumed at s=6)
        stageW64(wmh, HYP_, lds + STG, tid);
        SCHED0(); VMCNT4(); SCHED0(); SBAR(); SCHED0();
        __builtin_amdgcn_s_setprio(1);
        do_step32_fa(lds + H2S + 32768, lds + H1S, wm, wn, lsw, acc);
        __builtin_amdgcn_s_setprio(0);
        __syncthreads();                              // drains P2-W0 too
        epi_relu_lds(lds + H1S, acc, bs, wm, wn, lq, lr);
        __syncthreads();
    }

    // ---- P2: h2 = relu(h1 @ Wm^T + bm), K=256, 4 steps ----
    {
        f32x4 acc[4][4];
#pragma unroll
        for (int i = 0; i < 4; ++i)
#pragma unroll
            for (int j = 0; j < 4; ++j) acc[i][j] = zero;

        for (int s = 0; s < 3; ++s) {
            const int e = s + 1;
            stageW64(wmh + e * 64, HYP_, (e & 1) ? lds + H2S : lds + STG, tid);
            SCHED0(); VMCNT4(); SCHED0(); SBAR(); SCHED0();
            const char* ab = lds + H1S + s * 16384;
            const char* bb = (s & 1) ? lds + H2S : lds + STG;
            __builtin_amdgcn_s_setprio(1);
            do_step32(ab, bb, wm, wn, lsw, acc);
            __builtin_amdgcn_s_setprio(0);
            SCHED0(); SBAR(); SCHED0();
        }
        // s=3 (odd): pre-stage fc half-0 W0 -> STG (P2 W2 consumed at s=2)
        stageW64(weh, HYP_, lds + STG, tid);
        SCHED0(); VMCNT4(); SCHED0(); SBAR(); SCHED0();
        __builtin_amdgcn_s_setprio(1);
        do_step32(lds + H1S + 49152, lds + H2S, wm, wn, lsw, acc);
        __builtin_amdgcn_s_setprio(0);
        __syncthreads();                              // drains fc-W0
        epi_relu_lds(lds + H2S, acc, bm, wm, wn, lq, lr);
        __syncthreads();
    }

    // ---- P3/P4 per 256-col half: fc (4 BK=64 steps) + sig (16 BK=32) ----
#pragma unroll 1
    for (int half = 0; half < 2; ++half) {
        const int c0 = half * 256;
        const _Float16* wehh = weh + (size_t)c0 * HYP_;
        const _Float16* w2hh = w2h + (size_t)c0 * IN_;
        f32x4 accf[4][4], accs[4][4];
#pragma unroll
        for (int i = 0; i < 4; ++i)
#pragma unroll
            for (int j = 0; j < 4; ++j) { accf[i][j] = zero; accs[i][j] = zero; }

        // fc W0 pre-staged in STG (P2 s=3 / previous half's sig s=15)
        for (int s = 0; s < 3; ++s) {
            const int e = s + 1;
            stageW64(wehh + e * 64, HYP_, (e & 1) ? lds + H1S : lds + STG, tid);
            SCHED0(); VMCNT4(); SCHED0(); SBAR(); SCHED0();
            const char* ab = lds + H2S + s * 16384;
            const char* bb = (s & 1) ? lds + H1S : lds + STG;
            __builtin_amdgcn_s_setprio(1);
            do_step32(ab, bb, wm, wn, lsw, accf);
            __builtin_amdgcn_s_setprio(0);
            SCHED0(); SBAR(); SCHED0();
        }
        // fc s=3 (odd, W3 @H1S): pre-stage sig tile 0:
        //   A0(fp32, BK=32) -> H1S+32K ; W0(BK=32) -> STG+0 (fc W2 dead)
        {
            stageA32(xrow, IN_, lds + H1S + 32768, tid);
            stage512(w2hh, IN_, lds + STG, tid);
            SCHED0(); VMCNT4(); SCHED0(); SBAR(); SCHED0();
            __builtin_amdgcn_s_setprio(1);
            do_step32(lds + H2S + 49152, lds + H1S, wm, wn, lsw, accf);
            __builtin_amdgcn_s_setprio(0);
            SCHED0(); SBAR(); SCHED0();
        }
        // sig: 16 BK=32 steps, A = x fp32 (H1S+32K/48K), W even STG / odd H1S
        for (int s = 0; s < 15; ++s) {
            const int e = s + 1;
            stageA32(xrow + e * 32, IN_, lds + H1S + 32768 + (e & 1) * 16384, tid);
            stage512(w2hh + e * 32, IN_, (e & 1) ? lds + H1S : lds + STG, tid);
            SCHED0(); VMCNT4(); SCHED0(); SBAR(); SCHED0();
            const char* ab = lds + H1S + 32768 + (s & 1) * 16384;
            const char* bb = (s & 1) ? lds + H1S : lds + STG;
            __builtin_amdgcn_s_setprio(1);
            do_step16_fa(ab, bb, wm, wn, lsw, accs);
            __builtin_amdgcn_s_setprio(0);
            SCHED0(); SBAR(); SCHED0();
        }
        // sig s=15 (odd): pre-stage next half's fc W0 (half 0 only)
        if (half == 0) {
            stageW64(weh + (size_t)256 * HYP_, HYP_, lds + STG, tid);
            SCHED0(); VMCNT4();
        } else {
            VMCNT0();
        }
        SCHED0(); SBAR(); SCHED0();
        __builtin_amdgcn_s_setprio(1);
        do_step16_fa(lds + H1S + 32768 + 16384, lds + H1S, wm, wn, lsw, accs);
        __builtin_amdgcn_s_setprio(0);
        __syncthreads();                              // drains next fc-W0

        // epilogue: bh(fp16) = (fc + be) * sigmoid(sig + b2)
#pragma unroll
        for (int j = 0; j < 4; ++j) {
            const int gcol = c0 + wn * 64 + j * 16 + lr;
            const float bev = be[gcol];
            const float b2v = b2[gcol];
#pragma unroll
            for (int i = 0; i < 4; ++i) {
#pragma unroll
                for (int rg = 0; rg < 4; ++rg) {
                    const int row = m0 + wm * 64 + i * 16 + lq * 4 + rg;
                    const float fc = accf[i][j][rg] + bev;
                    float sg = accs[i][j][rg] + b2v;
                    sg = 1.f / (1.f + __expf(-sg));
                    bh[(size_t)row * HID_ + gcol] = (_Float16)(fc * sg);
                }
            }
        }
        __syncthreads();   // drains bh stores; protects H1S/STG for next half
    }

    // ---- tail: per-block segment (S,D) reduction (replaces seg_reduce) ----
    // Block rows = batch b, t in [t0, t0+128) = exactly segment t0/128.
    // bh tile just written by this block -> mostly L2-hot; ~half can evict
    // (32 blocks x 128KB = L2 capacity), so unroll 16 batches the loads to
    // cover HBM latency (r16's unroll-8 exposed ~6us of miss latency).
    {
        const int bb_ = m0 >> 10;          // batch
        const int t0  = m0 & 1023;         // segment start time
        const int seg = t0 >> 7;
        const int r   = tid;               // chain within batch
        const _Float16* bp = bh + (size_t)m0 * HID_;
        float S = 0.f, D = -__builtin_inff();
#pragma unroll 16
        for (int u = 0; u < SEGL; ++u) {
            const float v = (float)bp[u * 512 + ((r + t0 + u) & 511)];
            S += v;
            D = fmaxf(D + v, 0.f);
        }
        Sarr[seg * NCH + bb_ * 512 + r] = S;
        Darr[seg * NCH + bb_ * 512 + r] = D;
    }
}

// ---------------------------------------------------------------------------
// Segmented max-plus scan (proven r11): h' = relu(h + b) over a segment
// composes to h_out = max(h_in + S, D); (S,D) associative.
// ---------------------------------------------------------------------------
__global__ __launch_bounds__(64) void carry_scan(const float* __restrict__ hidden,
                                                 const float* __restrict__ Sarr,
                                                 const float* __restrict__ Darr,
                                                 float* __restrict__ carry,
                                                 float* __restrict__ hlast)
{
    const int chain = blockIdx.x * 64 + threadIdx.x;
    const int b = chain >> 9, r = chain & 511;
    float c = hidden[b * 512 + ((r + 511) & 511)];
#pragma unroll
    for (int j = 0; j < NSEG; ++j) {
        carry[j * NCH + chain] = c;
        c = fmaxf(c + Sarr[j * NCH + chain], Darr[j * NCH + chain]);
    }
    hlast[b * 512 + ((r + 1023) & 511)] = c;
}

__global__ __launch_bounds__(256) void seg_apply(const _Float16* __restrict__ bh,
                                                 const float* __restrict__ carry,
                                                 float* __restrict__ out)
{
    const int G = blockIdx.x * 256 + threadIdx.x;
    const int r = G & 511;
    const int seg = (G >> 9) & 7;
    const int b = G >> 12;
    const int chain = b * 512 + r;
    const _Float16* bb = bh + (size_t)b * (T_ * HID_);
    float* ob = out + (size_t)b * (T_ * HID_);
    const int t0 = seg * SEGL;

    float c = carry[seg * NCH + chain];
#pragma unroll 8
    for (int u = 0; u < SEGL; ++u) {
        const int t = t0 + u;
        const int idx = t * 512 + ((r + t) & 511);
        c = fmaxf(c + (float)bb[idx], 0.f);
        ob[idx] = c;
    }
}

extern "C" void kernel_launch(void* const* d_in, const int* in_sizes, int n_in,
                              void* d_out, int out_size, void* d_ws, size_t ws_size,
                              hipStream_t stream)
{
    const float* x      = (const float*)d_in[0];  // [B,T,IN]
    const float* hidden = (const float*)d_in[1];  // [B,HID]
    const float* Ws     = (const float*)d_in[2];  // [HYP,IN]
    const float* bs     = (const float*)d_in[3];
    const float* Wm     = (const float*)d_in[4];  // [HYP,HYP]
    const float* bm     = (const float*)d_in[5];
    const float* We     = (const float*)d_in[6];  // [HID,HYP]
    const float* be     = (const float*)d_in[7];
    const float* W2     = (const float*)d_in[8];  // [HID,IN]
    const float* b2     = (const float*)d_in[9];

    float* outputs = (float*)d_out;                 // [B,T,HID]
    float* hlast   = outputs + (size_t)M_ * HID_;   // [B,HID]

    // workspace: bh 32MB | weights 1.3MB | S,D,carry 1.5MB
    _Float16* bh   = (_Float16*)d_ws;
    _Float16* wsh  = bh + (size_t)M_ * HID_;        // [HYP,IN]
    _Float16* wmh  = wsh + HYP_ * IN_;              // [HYP,HYP]
    _Float16* weh  = wmh + HYP_ * HYP_;             // [HID,HYP]
    _Float16* w2h  = weh + HID_ * HYP_;             // [HID,IN]
    float*    Sarr = (float*)(w2h + HID_ * IN_);    // [NSEG, NCH]
    float*    Darr = Sarr + NSEG * NCH;             // [NSEG, NCH]
    float*    carr = Darr + NSEG * NCH;             // [NSEG, NCH]

    cvt_w<<<dim3(288), 256, 0, stream>>>(Ws, wsh, Wm, wmh, We, weh, W2, w2h);
    fused_mlp<<<dim3(M_ / R_), 512, 0, stream>>>(
        x, wsh, bs, wmh, bm, weh, be, w2h, b2, bh, Sarr, Darr);
    carry_scan<<<dim3(NCH / 64), 64, 0, stream>>>(hidden, Sarr, Darr, carr, hlast);
    seg_apply<<<dim3((NCH * NSEG) / 256), 256, 0, stream>>>(bh, carr, outputs);
}

// Round 19
// 108.523 us; speedup vs baseline: 1.0906x; 1.0251x over previous
//
#include <hip/hip_runtime.h>
#include <math.h>

#define B_   32
#define T_   1024
#define IN_  512
#define HID_ 512
#define HYP_ 256
#define M_   (B_ * T_)   // 32768
#define R_   128         // rows per fused block -> 256 blocks = 1/CU
#define NSEG 8
#define SEGL 128         // T_/NSEG == R_ -> one block = one segment
#define NCH  (B_ * HID_) // 16384 chains

// LDS map (bytes): H1S 64K | H2S 64K | STG 32K = 160 KiB exactly.
// Phase-dead buffer plan (each slot verified dead at staging time):
//  P1 : A(x fp32) dbuf -> H2S+0 / H2S+32K; W even->STG, odd->H1S+0
//  P2 : A=h1 (H1S, written by P1 epi); W even->STG, odd->H2S+0
//  fc : A=h2 (H2S, written by P2 epi); W even->STG, odd->H1S+0
//  sig: BK=32; A(x fp32) dbuf -> H1S+32K / H1S+48K; W even->STG+0,
//       odd->H1S+0.  H2S (h2) untouched -> survives for half 1.
#define H1S  0
#define H2S  65536
#define STG  131072
#define LDS_BYTES 163840

typedef _Float16 half8_t __attribute__((ext_vector_type(8)));
typedef float    f32x4   __attribute__((ext_vector_type(4)));

typedef __attribute__((address_space(1))) const void* gptr_as1;
typedef __attribute__((address_space(3))) void*       lptr_as3;

__device__ __forceinline__ void gload_lds16(const void* g, void* l) {
    __builtin_amdgcn_global_load_lds((gptr_as1)g, (lptr_as3)l, 16, 0, 0);
}

// counted-vmcnt (T4): literal = loads intentionally left in flight.
#define VMCNT8() asm volatile("s_waitcnt vmcnt(8)" ::: "memory")
#define VMCNT4() asm volatile("s_waitcnt vmcnt(4)" ::: "memory")
#define VMCNT0() asm volatile("s_waitcnt vmcnt(0)" ::: "memory")
#define SBAR()   __builtin_amdgcn_s_barrier()
#define SCHED0() __builtin_amdgcn_sched_barrier(0)

// ---------------------------------------------------------------------------
// fp32 -> fp16 weights only (~1.3 MB out). 2048 elems/block.
// Ws 131072 | Wm 65536 | We 131072 | W2 262144 -> 64|32|64|128 blocks.
// ---------------------------------------------------------------------------
__global__ __launch_bounds__(256) void cvt_w(
    const float* __restrict__ Ws, _Float16* __restrict__ wsh,
    const float* __restrict__ Wm, _Float16* __restrict__ wmh,
    const float* __restrict__ We, _Float16* __restrict__ weh,
    const float* __restrict__ W2, _Float16* __restrict__ w2h)
{
    const int blk = blockIdx.x;
    const float* src; _Float16* dst; int base;
    if      (blk < 64)  { src = Ws; dst = wsh; base = blk; }
    else if (blk < 96)  { src = Wm; dst = wmh; base = blk - 64; }
    else if (blk < 160) { src = We; dst = weh; base = blk - 96; }
    else                { src = W2; dst = w2h; base = blk - 160; }
    const int i = base * 2048 + threadIdx.x * 8;
    f32x4 v0 = *(const f32x4*)(src + i);
    f32x4 v1 = *(const f32x4*)(src + i + 4);
    half8_t h;
    h[0] = (_Float16)v0[0]; h[1] = (_Float16)v0[1];
    h[2] = (_Float16)v0[2]; h[3] = (_Float16)v0[3];
    h[4] = (_Float16)v1[0]; h[5] = (_Float16)v1[1];
    h[6] = (_Float16)v1[2]; h[7] = (_Float16)v1[3];
    *(half8_t*)(dst + i) = h;
}

// ---------------------------------------------------------------------------
// Fragment-order + XOR-swizzled W staging (proven r8 layout).
// stage512: 256-row x 32-half W sub-tile (16 KiB), 2 gload_lds/thread.
// stageW64: 64-half W tile (32 KiB) = two sub-tiles -> 4/thread.
// ---------------------------------------------------------------------------
__device__ __forceinline__ void stage512(const _Float16* src, int K,
                                         char* ldsbase, int tid)
{
#pragma unroll
    for (int q = 0; q < 2; ++q) {
        const int s = q * 512 + tid;
        const int g = s >> 6, c2 = (s >> 4) & 3, r = (s & 15) ^ c2;
        const char* gp = (const char*)src + (size_t)(g * 16 + r) * (K * 2) + c2 * 16;
        char* lp = ldsbase + (q * 512 + (tid & ~63)) * 16;
        gload_lds16(gp, lp);
    }
}

__device__ __forceinline__ void stageW64(const _Float16* src, int K,
                                         char* ldsbase, int tid)
{
    stage512(src,      K, ldsbase,         tid);
    stage512(src + 32, K, ldsbase + 16384, tid);
}

// ---------------------------------------------------------------------------
// fp32 A staging via gload_lds, plane-split: one BK=32 sub-tile (128 rows x
// 32 floats) = 16 KiB = two 8 KiB planes; plane p holds floats k%8 in
// [4p,4p+4). Each plane uses the SAME slot map + XOR swizzle as the fp16
// tile (16B slot = 4 floats), so the proven conflict-free read offset lsw
// applies unchanged. 2 gload_lds/thread per sub-tile. ASYNC.
// ---------------------------------------------------------------------------
__device__ __forceinline__ void stageA32(const float* src, int K,
                                         char* ldsbase, int tid)
{
#pragma unroll
    for (int p = 0; p < 2; ++p) {
        const int g = tid >> 6, c2 = (tid >> 4) & 3, r = (tid & 15) ^ c2;
        const char* gp = (const char*)(src + (size_t)(g * 16 + r) * K + c2 * 8 + p * 4);
        char* lp = ldsbase + p * 8192 + (tid & ~63) * 16;
        gload_lds16(gp, lp);
    }
}

// BK=64 fp32 A tile (32 KiB): two sub-tiles at +0 / +16K -> 4 loads/thread
__device__ __forceinline__ void stageA32_64(const float* src, int K,
                                            char* ldsbase, int tid)
{
    stageA32(src,      K, ldsbase,         tid);
    stageA32(src + 32, K, ldsbase + 16384, tid);
}

__device__ __forceinline__ half8_t cvt8(f32x4 a, f32x4 b)
{
    half8_t h;
    h[0] = (_Float16)a[0]; h[1] = (_Float16)a[1];
    h[2] = (_Float16)a[2]; h[3] = (_Float16)a[3];
    h[4] = (_Float16)b[0]; h[5] = (_Float16)b[1];
    h[6] = (_Float16)b[2]; h[7] = (_Float16)b[3];
    return h;
}

// 16 MFMAs, fp16 A sub-tile (h1/h2 paths)
__device__ __forceinline__ void do_step16(const char* ab, const char* bb,
                                          int wm, int wn, int lsw,
                                          f32x4 acc[4][4])
{
    half8_t af[4], wf[4];
#pragma unroll
    for (int i = 0; i < 4; ++i)
        af[i] = *(const half8_t*)(ab + (wm * 4 + i) * 1024 + lsw);
#pragma unroll
    for (int j = 0; j < 4; ++j)
        wf[j] = *(const half8_t*)(bb + (wn * 4 + j) * 1024 + lsw);
#pragma unroll
    for (int i = 0; i < 4; ++i)
#pragma unroll
        for (int j = 0; j < 4; ++j)
            acc[i][j] = __builtin_amdgcn_mfma_f32_16x16x32_f16(af[i], wf[j], acc[i][j], 0, 0, 0);
}

__device__ __forceinline__ void do_step32(const char* ab, const char* bb,
                                          int wm, int wn, int lsw,
                                          f32x4 acc[4][4])
{
    do_step16(ab,         bb,         wm, wn, lsw, acc);
    do_step16(ab + 8192,  bb + 16384, wm, wn, lsw, acc);
}

// 16 MFMAs, fp32 A sub-tile (x paths): 2 plane reads + cvt per A-frag
__device__ __forceinline__ void do_step16_fa(const char* ab, const char* bb,
                                             int wm, int wn, int lsw,
                                             f32x4 acc[4][4])
{
    half8_t af[4], wf[4];
#pragma unroll
    for (int i = 0; i < 4; ++i) {
        f32x4 p0 = *(const f32x4*)(ab + (wm * 4 + i) * 1024 + lsw);
        f32x4 p1 = *(const f32x4*)(ab + 8192 + (wm * 4 + i) * 1024 + lsw);
        af[i] = cvt8(p0, p1);
    }
#pragma unroll
    for (int j = 0; j < 4; ++j)
        wf[j] = *(const half8_t*)(bb + (wn * 4 + j) * 1024 + lsw);
#pragma unroll
    for (int i = 0; i < 4; ++i)
#pragma unroll
        for (int j = 0; j < 4; ++j)
            acc[i][j] = __builtin_amdgcn_mfma_f32_16x16x32_f16(af[i], wf[j], acc[i][j], 0, 0, 0);
}

__device__ __forceinline__ void do_step32_fa(const char* ab, const char* bb,
                                             int wm, int wn, int lsw,
                                             f32x4 acc[4][4])
{
    do_step16_fa(ab,          bb,         wm, wn, lsw, acc);
    do_step16_fa(ab + 16384,  bb + 16384, wm, wn, lsw, acc);
}

// bias+relu epilogue: scatter fp16 into XOR-swizzled fragment-order LDS
__device__ __forceinline__ void epi_relu_lds(char* dst, const f32x4 acc[4][4],
                                             const float* __restrict__ bias,
                                             int wm, int wn, int lq, int lr)
{
#pragma unroll
    for (int j = 0; j < 4; ++j) {
        const int col = wn * 64 + j * 16 + lr;
        const float bv = bias[col];
        const int cc2 = (col & 31) >> 3;
        const int cpart = (col >> 5) * 8192 + cc2 * 256 + (col & 7) * 2;
#pragma unroll
        for (int i = 0; i < 4; ++i) {
#pragma unroll
            for (int rg = 0; rg < 4; ++rg) {
                const int row = wm * 64 + i * 16 + lq * 4 + rg;
                const float v = fmaxf(acc[i][j][rg] + bv, 0.f);
                *(_Float16*)(dst + cpart + (row >> 4) * 1024 +
                             (((row & 15) ^ cc2)) * 16) = (_Float16)v;
            }
        }
    }
}

// ---------------------------------------------------------------------------
// Fused MLP (r14 proven structure) + in-kernel segment (S,D) reduction tail.
//   P1 : h1 = relu(x@Ws^T+bs)   K=512, 8 BK=64 steps (A fp32 + W), VMCNT(8)
//   P2 : h2 = relu(h1@Wm^T+bm)  K=256, 4 BK=64 steps, VMCNT(4)
//   fc : (per half) 4 BK=64 steps, A=h2, VMCNT(4)
//   sig: (per half) 16 BK=32 steps, A=x fp32, VMCNT(4)
// Tail: block covers rows t0..t0+127 of batch b = exactly segment t0/128 for
// all 512 chains -> reduce (S,D) from the freshly-written (L2-hot) bh tile.
// ---------------------------------------------------------------------------
__global__ __launch_bounds__(512, 2) void fused_mlp(
    const float* __restrict__ x,
    const _Float16* __restrict__ wsh, const float* __restrict__ bs,
    const _Float16* __restrict__ wmh, const float* __restrict__ bm,
    const _Float16* __restrict__ weh, const float* __restrict__ be,
    const _Float16* __restrict__ w2h, const float* __restrict__ b2,
    _Float16* __restrict__ bh,
    float* __restrict__ Sarr, float* __restrict__ Darr)
{
    __shared__ __align__(16) char lds[LDS_BYTES];

    const int tid  = threadIdx.x;
    const int m0   = blockIdx.x * R_;
    const int lane = tid & 63;
    const int wave = tid >> 6;
    const int wm = wave >> 2;
    const int wn = wave & 3;
    const int lq = lane >> 4, lr = lane & 15;
    const int lsw = (lane ^ ((lane >> 4) & 3)) * 16;

    const float* xrow = x + (size_t)m0 * IN_;
    const f32x4 zero = {0.f, 0.f, 0.f, 0.f};

    // ---- P1: h1 = relu(x @ Ws^T + bs), K=512, 8 steps of 64 ----
    {
        f32x4 acc[4][4];
#pragma unroll
        for (int i = 0; i < 4; ++i)
#pragma unroll
            for (int j = 0; j < 4; ++j) acc[i][j] = zero;

        stageA32_64(xrow, IN_, lds + H2S, tid);       // A0 -> H2S slot0
        stageW64(wsh, IN_, lds + STG, tid);           // W0 even -> STG
        __syncthreads();                              // drain prologue

        for (int s = 0; s < 7; ++s) {
            const int e = s + 1;
            stageA32_64(xrow + e * 64, IN_, lds + H2S + (e & 1) * 32768, tid);
            stageW64(wsh + e * 64, IN_, (e & 1) ? lds + H1S : lds + STG, tid);
            SCHED0(); VMCNT8(); SCHED0(); SBAR(); SCHED0();
            const char* ab = lds + H2S + (s & 1) * 32768;
            const char* bb = (s & 1) ? lds + H1S : lds + STG;
            __builtin_amdgcn_s_setprio(1);
            do_step32_fa(ab, bb, wm, wn, lsw, acc);
            __builtin_amdgcn_s_setprio(0);
            SCHED0(); SBAR(); SCHED0();
        }
        // s=7 (odd): pre-stage P2's W0 -> STG (P1 W6 in STG consumed at s=6)
        stageW64(wmh, HYP_, lds + STG, tid);
        SCHED0(); VMCNT4(); SCHED0(); SBAR(); SCHED0();
        __builtin_amdgcn_s_setprio(1);
        do_step32_fa(lds + H2S + 32768, lds + H1S, wm, wn, lsw, acc);
        __builtin_amdgcn_s_setprio(0);
        __syncthreads();                              // drains P2-W0 too
        epi_relu_lds(lds + H1S, acc, bs, wm, wn, lq, lr);
        __syncthreads();
    }

    // ---- P2: h2 = relu(h1 @ Wm^T + bm), K=256, 4 steps ----
    {
        f32x4 acc[4][4];
#pragma unroll
        for (int i = 0; i < 4; ++i)
#pragma unroll
            for (int j = 0; j < 4; ++j) acc[i][j] = zero;

        for (int s = 0; s < 3; ++s) {
            const int e = s + 1;
            stageW64(wmh + e * 64, HYP_, (e & 1) ? lds + H2S : lds + STG, tid);
            SCHED0(); VMCNT4(); SCHED0(); SBAR(); SCHED0();
            const char* ab = lds + H1S + s * 16384;
            const char* bb = (s & 1) ? lds + H2S : lds + STG;
            __builtin_amdgcn_s_setprio(1);
            do_step32(ab, bb, wm, wn, lsw, acc);
            __builtin_amdgcn_s_setprio(0);
            SCHED0(); SBAR(); SCHED0();
        }
        // s=3 (odd): pre-stage fc half-0 W0 -> STG (P2 W2 consumed at s=2)
        stageW64(weh, HYP_, lds + STG, tid);
        SCHED0(); VMCNT4(); SCHED0(); SBAR(); SCHED0();
        __builtin_amdgcn_s_setprio(1);
        do_step32(lds + H1S + 49152, lds + H2S, wm, wn, lsw, acc);
        __builtin_amdgcn_s_setprio(0);
        __syncthreads();                              // drains fc-W0
        epi_relu_lds(lds + H2S, acc, bm, wm, wn, lq, lr);
        __syncthreads();
    }

    // ---- P3/P4 per 256-col half: fc (4 BK=64 steps) + sig (16 BK=32) ----
#pragma unroll 1
    for (int half = 0; half < 2; ++half) {
        const int c0 = half * 256;
        const _Float16* wehh = weh + (size_t)c0 * HYP_;
        const _Float16* w2hh = w2h + (size_t)c0 * IN_;
        f32x4 accf[4][4], accs[4][4];
#pragma unroll
        for (int i = 0; i < 4; ++i)
#pragma unroll
            for (int j = 0; j < 4; ++j) { accf[i][j] = zero; accs[i][j] = zero; }

        // fc W0 pre-staged in STG (P2 s=3 / previous half's sig s=15)
        for (int s = 0; s < 3; ++s) {
            const int e = s + 1;
            stageW64(wehh + e * 64, HYP_, (e & 1) ? lds + H1S : lds + STG, tid);
            SCHED0(); VMCNT4(); SCHED0(); SBAR(); SCHED0();
            const char* ab = lds + H2S + s * 16384;
            const char* bb = (s & 1) ? lds + H1S : lds + STG;
            __builtin_amdgcn_s_setprio(1);
            do_step32(ab, bb, wm, wn, lsw, accf);
            __builtin_amdgcn_s_setprio(0);
            SCHED0(); SBAR(); SCHED0();
        }
        // fc s=3 (odd, W3 @H1S): pre-stage sig tile 0:
        //   A0(fp32, BK=32) -> H1S+32K ; W0(BK=32) -> STG+0 (fc W2 dead)
        {
            stageA32(xrow, IN_, lds + H1S + 32768, tid);
            stage512(w2hh, IN_, lds + STG, tid);
            SCHED0(); VMCNT4(); SCHED0(); SBAR(); SCHED0();
            __builtin_amdgcn_s_setprio(1);
            do_step32(lds + H2S + 49152, lds + H1S, wm, wn, lsw, accf);
            __builtin_amdgcn_s_setprio(0);
            SCHED0(); SBAR(); SCHED0();
        }
        // sig: 16 BK=32 steps, A = x fp32 (H1S+32K/48K), W even STG / odd H1S
        for (int s = 0; s < 15; ++s) {
            const int e = s + 1;
            stageA32(xrow + e * 32, IN_, lds + H1S + 32768 + (e & 1) * 16384, tid);
            stage512(w2hh + e * 32, IN_, (e & 1) ? lds + H1S : lds + STG, tid);
            SCHED0(); VMCNT4(); SCHED0(); SBAR(); SCHED0();
            const char* ab = lds + H1S + 32768 + (s & 1) * 16384;
            const char* bb = (s & 1) ? lds + H1S : lds + STG;
            __builtin_amdgcn_s_setprio(1);
            do_step16_fa(ab, bb, wm, wn, lsw, accs);
            __builtin_amdgcn_s_setprio(0);
            SCHED0(); SBAR(); SCHED0();
        }
        // sig s=15 (odd): pre-stage next half's fc W0 (half 0 only)
        if (half == 0) {
            stageW64(weh + (size_t)256 * HYP_, HYP_, lds + STG, tid);
            SCHED0(); VMCNT4();
        } else {
            VMCNT0();
        }
        SCHED0(); SBAR(); SCHED0();
        __builtin_amdgcn_s_setprio(1);
        do_step16_fa(lds + H1S + 32768 + 16384, lds + H1S, wm, wn, lsw, accs);
        __builtin_amdgcn_s_setprio(0);
        __syncthreads();                              // drains next fc-W0

        // epilogue: bh(fp16) = (fc + be) * sigmoid(sig + b2)
#pragma unroll
        for (int j = 0; j < 4; ++j) {
            const int gcol = c0 + wn * 64 + j * 16 + lr;
            const float bev = be[gcol];
            const float b2v = b2[gcol];
#pragma unroll
            for (int i = 0; i < 4; ++i) {
#pragma unroll
                for (int rg = 0; rg < 4; ++rg) {
                    const int row = m0 + wm * 64 + i * 16 + lq * 4 + rg;
                    const float fc = accf[i][j][rg] + bev;
                    float sg = accs[i][j][rg] + b2v;
                    sg = 1.f / (1.f + __expf(-sg));
                    bh[(size_t)row * HID_ + gcol] = (_Float16)(fc * sg);
                }
            }
        }
        __syncthreads();   // drains bh stores; protects H1S/STG for next half
    }

    // ---- tail: per-block segment (S,D) reduction (replaces seg_reduce) ----
    // Block rows = batch b, t in [t0, t0+128) = exactly segment t0/128.
    // unroll 16 batches the loads to cover latency on L2-evicted lines.
    {
        const int bb_ = m0 >> 10;          // batch
        const int t0  = m0 & 1023;         // segment start time
        const int seg = t0 >> 7;
        const int r   = tid;               // chain within batch
        const _Float16* bp = bh + (size_t)m0 * HID_;
        float S = 0.f, D = -__builtin_inff();
#pragma unroll 16
        for (int u = 0; u < SEGL; ++u) {
            const float v = (float)bp[u * 512 + ((r + t0 + u) & 511)];
            S += v;
            D = fmaxf(D + v, 0.f);
        }
        Sarr[seg * NCH + bb_ * 512 + r] = S;
        Darr[seg * NCH + bb_ * 512 + r] = D;
    }
}

// ---------------------------------------------------------------------------
// seg_apply with inlined carry prefix (replaces the separate carry_scan):
// each thread composes its own carry from Sarr/Darr (<=7 max-plus ops,
// wave-uniform loop bound, coalesced reads), then runs the exact sequential
// recurrence within its segment. seg==7 threads finish holding h_{1023} and
// write hlast (column (r+1023)&511).
// ---------------------------------------------------------------------------
__global__ __launch_bounds__(256) void seg_apply(const _Float16* __restrict__ bh,
                                                 const float* __restrict__ Sarr,
                                                 const float* __restrict__ Darr,
                                                 const float* __restrict__ hidden,
                                                 float* __restrict__ out,
                                                 float* __restrict__ hlast)
{
    const int G = blockIdx.x * 256 + threadIdx.x;
    const int r = G & 511;
    const int seg = (G >> 9) & 7;
    const int b = G >> 12;
    const int chain = b * 512 + r;
    const _Float16* bb = bh + (size_t)b * (T_ * HID_);
    float* ob = out + (size_t)b * (T_ * HID_);
    const int t0 = seg * SEGL;

    // carry prefix: c = h_{t0-1} along chain r
    float c = hidden[b * 512 + ((r + 511) & 511)];
    for (int j = 0; j < seg; ++j)   // wave-uniform bound (seg const per wave)
        c = fmaxf(c + Sarr[j * NCH + chain], Darr[j * NCH + chain]);

#pragma unroll 8
    for (int u = 0; u < SEGL; ++u) {
        const int t = t0 + u;
        const int idx = t * 512 + ((r + t) & 511);
        c = fmaxf(c + (float)bb[idx], 0.f);
        ob[idx] = c;
    }
    if (seg == NSEG - 1)
        hlast[b * 512 + ((r + 1023) & 511)] = c;   // c == h_{T-1} of chain r
}

extern "C" void kernel_launch(void* const* d_in, const int* in_sizes, int n_in,
                              void* d_out, int out_size, void* d_ws, size_t ws_size,
                              hipStream_t stream)
{
    const float* x      = (const float*)d_in[0];  // [B,T,IN]
    const float* hidden = (const float*)d_in[1];  // [B,HID]
    const float* Ws     = (const float*)d_in[2];  // [HYP,IN]
    const float* bs     = (const float*)d_in[3];
    const float* Wm     = (const float*)d_in[4];  // [HYP,HYP]
    const float* bm     = (const float*)d_in[5];
    const float* We     = (const float*)d_in[6];  // [HID,HYP]
    const float* be     = (const float*)d_in[7];
    const float* W2     = (const float*)d_in[8];  // [HID,IN]
    const float* b2     = (const float*)d_in[9];

    float* outputs = (float*)d_out;                 // [B,T,HID]
    float* hlast   = outputs + (size_t)M_ * HID_;   // [B,HID]

    // workspace: bh 32MB | weights 1.3MB | S,D 1MB
    _Float16* bh   = (_Float16*)d_ws;
    _Float16* wsh  = bh + (size_t)M_ * HID_;        // [HYP,IN]
    _Float16* wmh  = wsh + HYP_ * IN_;              // [HYP,HYP]
    _Float16* weh  = wmh + HYP_ * HYP_;             // [HID,HYP]
    _Float16* w2h  = weh + HID_ * HYP_;             // [HID,IN]
    float*    Sarr = (float*)(w2h + HID_ * IN_);    // [NSEG, NCH]
    float*    Darr = Sarr + NSEG * NCH;             // [NSEG, NCH]

    cvt_w<<<dim3(288), 256, 0, stream>>>(Ws, wsh, Wm, wmh, We, weh, W2, w2h);
    fused_mlp<<<dim3(M_ / R_), 512, 0, stream>>>(
        x, wsh, bs, wmh, bm, weh, be, w2h, b2, bh, Sarr, Darr);
    seg_apply<<<dim3((NCH * NSEG) / 256), 256, 0, stream>>>(
        bh, Sarr, Darr, hidden, outputs, hlast);
}